// Round 12
// baseline (97.339 us; speedup 1.0000x reference)
//
#include <hip/hip_runtime.h>

#define NSTEPS 24
#define HALFW  2048
#define INV2PI 0.15915494309189535f

typedef float float2v __attribute__((ext_vector_type(2)));

// R10 swizzle (bijective triangular XOR) — verified per-16-lane-injective
// for all four maps; measured 2.1M conflict-cycles (~3.4us/CU, acceptable).
#define SWZ(q) ((q) ^ (((q) >> 4) & 31) ^ (((q) >> 3) & 8))

// Phase maps for 512 threads x 8 elems (R10-verified): lane bits stay in
// q[3:0] at load (QA) and store (QD) phases => dense coalescing.
#define QA(e) (((e) << 9) | t)                                  // e in 11..9
#define QB(e) ((((t) >> 6) << 9) | ((e) << 6) | ((t) & 63))     // e in 8..6
#define QC(e) ((((t) >> 3) << 6) | ((e) << 3) | ((t) & 7))      // e in 5..3
#define QD(e) (((t) << 3) | (e))                                // e in 2..0

#define SB() __builtin_amdgcn_sched_barrier(0)

// tab[d*2048 + t*4 + p] = theta/(2*pi). R10-verified derivation (PERM =
// ror12; step d butterflies bit 11-(d%12); l = rotl12(q0, d%12) & 0x7FF).
__global__ void build_tab_kernel(const float* __restrict__ params,
                                 float* __restrict__ tab) {
    int idx = blockIdx.x * 256 + threadIdx.x;
    if (idx >= NSTEPS * HALFW) return;
    int d  = idx >> 11;
    int j  = idx & (HALFW - 1);
    int t  = j >> 2;              // 0..511
    int p  = j & 3;               // pair index (2 bits)
    int ph = d / 3;               // phase 0..7, map = ph & 3
    int k  = 2 - (d % 3);         // butterfly bit within the 3-bit group
    int e0 = ((p >> k) << (k + 1)) | (p & ((1 << k) - 1)); // insert 0 at bit k
    int q0;
    switch (ph & 3) {
        case 0:  q0 = (e0 << 9) | t; break;
        case 1:  q0 = ((t >> 6) << 9) | (e0 << 6) | (t & 63); break;
        case 2:  q0 = ((t >> 3) << 6) | (e0 << 3) | (t & 7); break;
        default: q0 = (t << 3) | e0; break;
    }
    int dd = d % 12;
    int l = ((q0 << dd) | (q0 >> (12 - dd))) & 0xFFF;       // rotl12(q0, dd)
    l &= 0x7FF;
    float theta = params[l * NSTEPS + d];   // params (2048, 24) row-major
    tab[idx] = theta * INV2PI;
}

// 4-float theta load (one dwordx4, SROA-safe scalar unpack).
__device__ __forceinline__ void ldth4(float (&dst)[4], const float* __restrict__ p) {
    float4 q = *(const float4*)p;
    dst[0] = q.x; dst[1] = q.y; dst[2] = q.z; dst[3] = q.w;
}

// Packed butterfly on bit KK applied to BOTH pipelines (4 rows) with ONE
// sincos evaluation (column-determined, row-independent). 8 independent
// pk-FMA chains per p: high ILP.
template<int KK>
__device__ __forceinline__ void bfly2(float2v (&ra)[8], float2v (&rb)[8],
                                      const float (&th)[4]) {
    #pragma unroll
    for (int p = 0; p < 4; ++p) {
        const int e0 = ((p >> KK) << (KK + 1)) | (p & ((1 << KK) - 1));
        const int e1 = e0 | (1 << KK);
        const float c = __builtin_amdgcn_cosf(th[p]);
        const float s = __builtin_amdgcn_sinf(th[p]);
        const float2v cv = {c, c};
        const float2v sv = {s, s};
        const float2v a0 = ra[e0], a1 = ra[e1];
        ra[e0] = __builtin_elementwise_fma(cv, a0, sv * a1);
        ra[e1] = __builtin_elementwise_fma(cv, a1, -(sv * a0));
        const float2v b0 = rb[e0], b1 = rb[e1];
        rb[e0] = __builtin_elementwise_fma(cv, b0, sv * b1);
        rb[e1] = __builtin_elementwise_fma(cv, b1, -(sv * b0));
    }
}

// 3 butterfly steps (one phase) on both pipelines; theta dbuf te/to,
// distance-2 prefetch pinned after each last use (proven SB pattern).
template<int BASE>
__device__ __forceinline__ void group3(float2v (&ra)[8], float2v (&rb)[8],
        float (&te)[4], float (&to)[4], const float* __restrict__ tb) {
    if constexpr ((BASE & 1) == 0) {
        bfly2<2>(ra, rb, te);
        if constexpr (BASE + 2 < NSTEPS) { ldth4(te, tb + (BASE + 2) * 2048); SB(); }
        bfly2<1>(ra, rb, to);
        if constexpr (BASE + 3 < NSTEPS) { ldth4(to, tb + (BASE + 3) * 2048); SB(); }
        bfly2<0>(ra, rb, te);
        if constexpr (BASE + 4 < NSTEPS) { ldth4(te, tb + (BASE + 4) * 2048); SB(); }
    } else {
        bfly2<2>(ra, rb, to);
        if constexpr (BASE + 2 < NSTEPS) { ldth4(to, tb + (BASE + 2) * 2048); SB(); }
        bfly2<1>(ra, rb, te);
        if constexpr (BASE + 3 < NSTEPS) { ldth4(te, tb + (BASE + 3) * 2048); SB(); }
        bfly2<0>(ra, rb, to);
        if constexpr (BASE + 4 < NSTEPS) { ldth4(to, tb + (BASE + 4) * 2048); SB(); }
    }
}

// Both pipelines share ONE 32 KiB b64 buffer, transposed back-to-back.
// Hazards: wA->rA cross-thread (sync1); rA->wB cross-thread (sync2);
// wB->rB cross-thread (sync3); rB->next wA same-thread (R9 bijection).
#define TRANS(QS, QDm) do {                                                   \
    _Pragma("unroll")                                                         \
    for (int e = 0; e < 8; ++e)                                               \
        lds[SWZ(QS(e))] = rpA[e];                                             \
    __syncthreads();                                                          \
    _Pragma("unroll")                                                         \
    for (int e = 0; e < 8; ++e)                                               \
        rpA[e] = lds[SWZ(QDm(e))];                                            \
    __syncthreads();                                                          \
    _Pragma("unroll")                                                         \
    for (int e = 0; e < 8; ++e)                                               \
        lds[SWZ(QS(e))] = rpB[e];                                             \
    __syncthreads();                                                         \
    _Pragma("unroll")                                                         \
    for (int e = 0; e < 8; ++e)                                               \
        rpB[e] = lds[SWZ(QDm(e))];                                            \
} while (0)

// Tier math (validated R10/R11): 24 waves/CU = 6 waves/SIMD needs VGPR <=
// floor(256/6) = 42. R11 allocated 44 with ~40 essential data regs — the
// 2-reg trim is address-remat, not data spill (NOT an R1-style squeeze).
// (512,6) requests exactly the 3-blocks/CU point.
__global__ __launch_bounds__(512, 6)
void bfly_kernel(const float* __restrict__ X,
                 const float* __restrict__ tab,
                 float* __restrict__ Y) {
    __shared__ float2v lds[4096];      // 32 KiB, shared by both pipelines
    const int t = threadIdx.x;
    const size_t row0 = (size_t)blockIdx.x * 4;

    const float* tb = tab + t * 4;
    float te[4], to[4];
    ldth4(te, tb + 0 * 2048);
    ldth4(to, tb + 1 * 2048);
    SB();

    float2v rpA[8], rpB[8];            // A: rows 0,1  B: rows 2,3
    {
        const float* x0 = X + row0 * 4096;
        const float* x1 = x0 + 4096;
        const float* x2 = x0 + 8192;
        const float* x3 = x0 + 12288;
        #pragma unroll
        for (int e = 0; e < 8; ++e) {
            const int a = QA(e);   // consecutive lanes, consecutive addresses
            rpA[e].x = x0[a];
            rpA[e].y = x1[a];
            rpB[e].x = x2[a];
            rpB[e].y = x3[a];
        }
    }

    group3<0 >(rpA, rpB, te, to, tb);   TRANS(QA, QB);   // steps 0..2   bits 11..9
    group3<3 >(rpA, rpB, te, to, tb);   TRANS(QB, QC);   // steps 3..5   bits 8..6
    group3<6 >(rpA, rpB, te, to, tb);   TRANS(QC, QD);   // steps 6..8   bits 5..3
    group3<9 >(rpA, rpB, te, to, tb);   TRANS(QD, QA);   // steps 9..11  bits 2..0
    group3<12>(rpA, rpB, te, to, tb);   TRANS(QA, QB);   // steps 12..14 bits 11..9
    group3<15>(rpA, rpB, te, to, tb);   TRANS(QB, QC);   // steps 15..17 bits 8..6
    group3<18>(rpA, rpB, te, to, tb);   TRANS(QC, QD);   // steps 18..20 bits 5..3
    group3<21>(rpA, rpB, te, to, tb);                    // steps 21..23 bits 2..0

    // QD layout: thread t holds 8 consecutive columns at t*8, 4 rows.
    {
        float* y0 = Y + row0 * 4096 + (t << 3);
        float* y1 = y0 + 4096;
        float* y2 = y0 + 8192;
        float* y3 = y0 + 12288;
        float4 v;
        v.x = rpA[0].x; v.y = rpA[1].x; v.z = rpA[2].x; v.w = rpA[3].x;
        *(float4*)&y0[0] = v;
        v.x = rpA[4].x; v.y = rpA[5].x; v.z = rpA[6].x; v.w = rpA[7].x;
        *(float4*)&y0[4] = v;
        v.x = rpA[0].y; v.y = rpA[1].y; v.z = rpA[2].y; v.w = rpA[3].y;
        *(float4*)&y1[0] = v;
        v.x = rpA[4].y; v.y = rpA[5].y; v.z = rpA[6].y; v.w = rpA[7].y;
        *(float4*)&y1[4] = v;
        v.x = rpB[0].x; v.y = rpB[1].x; v.z = rpB[2].x; v.w = rpB[3].x;
        *(float4*)&y2[0] = v;
        v.x = rpB[4].x; v.y = rpB[5].x; v.z = rpB[6].x; v.w = rpB[7].x;
        *(float4*)&y2[4] = v;
        v.x = rpB[0].y; v.y = rpB[1].y; v.z = rpB[2].y; v.w = rpB[3].y;
        *(float4*)&y3[0] = v;
        v.x = rpB[4].y; v.y = rpB[5].y; v.z = rpB[6].y; v.w = rpB[7].y;
        *(float4*)&y3[4] = v;
    }
}

extern "C" void kernel_launch(void* const* d_in, const int* in_sizes, int n_in,
                              void* d_out, int out_size, void* d_ws, size_t ws_size,
                              hipStream_t stream) {
    const float* X      = (const float*)d_in[0];
    const float* params = (const float*)d_in[1];
    float* out = (float*)d_out;
    float* tab = (float*)d_ws;   // 24*2048*4 = 196,608 bytes (theta only)

    hipLaunchKernelGGL(build_tab_kernel,
                       dim3((NSTEPS * HALFW + 255) / 256), dim3(256), 0, stream,
                       params, tab);
    hipLaunchKernelGGL(bfly_kernel,
                       dim3(8192 / 4), dim3(512), 0, stream,
                       X, tab, out);
}

// Round 13
// 91.806 us; speedup vs baseline: 1.0603x; 1.0603x over previous
//
#include <hip/hip_runtime.h>

#define NSTEPS 24
#define HALFW  2048
#define INV2PI 0.15915494309189535f

typedef float float2v __attribute__((ext_vector_type(2)));

// R10 swizzle (bijective triangular XOR) — verified per-16-lane-injective
// for all four maps; measured 2.1M conflict-cycles (~3.4us/CU, acceptable).
#define SWZ(q) ((q) ^ (((q) >> 4) & 31) ^ (((q) >> 3) & 8))

// Phase maps for 512 threads x 8 elems (R10-verified): lane bits stay in
// q[3:0] at load (QA) and store (QD) phases => dense coalescing.
#define QA(e) (((e) << 9) | t)                                  // e in 11..9
#define QB(e) ((((t) >> 6) << 9) | ((e) << 6) | ((t) & 63))     // e in 8..6
#define QC(e) ((((t) >> 3) << 6) | ((e) << 3) | ((t) & 7))      // e in 5..3
#define QD(e) (((t) << 3) | (e))                                // e in 2..0

#define SB() __builtin_amdgcn_sched_barrier(0)

// tab[d*2048 + t*4 + p] = theta/(2*pi). R10/R11-verified derivation.
__global__ void build_tab_kernel(const float* __restrict__ params,
                                 float* __restrict__ tab) {
    int idx = blockIdx.x * 256 + threadIdx.x;
    if (idx >= NSTEPS * HALFW) return;
    int d  = idx >> 11;
    int j  = idx & (HALFW - 1);
    int t  = j >> 2;              // 0..511
    int p  = j & 3;               // pair index (2 bits)
    int ph = d / 3;               // phase 0..7, map = ph & 3
    int k  = 2 - (d % 3);         // butterfly bit within the 3-bit group
    int e0 = ((p >> k) << (k + 1)) | (p & ((1 << k) - 1)); // insert 0 at bit k
    int q0;
    switch (ph & 3) {
        case 0:  q0 = (e0 << 9) | t; break;
        case 1:  q0 = ((t >> 6) << 9) | (e0 << 6) | (t & 63); break;
        case 2:  q0 = ((t >> 3) << 6) | (e0 << 3) | (t & 7); break;
        default: q0 = (t << 3) | e0; break;
    }
    int dd = d % 12;
    int l = ((q0 << dd) | (q0 >> (12 - dd))) & 0xFFF;       // rotl12(q0, dd)
    l &= 0x7FF;
    float theta = params[l * NSTEPS + d];   // params (2048, 24) row-major
    tab[idx] = theta * INV2PI;
}

// 4-float theta load (one dwordx4, SROA-safe scalar unpack).
__device__ __forceinline__ void ldth4(float (&dst)[4], const float* __restrict__ p) {
    float4 q = *(const float4*)p;
    dst[0] = q.x; dst[1] = q.y; dst[2] = q.z; dst[3] = q.w;
}

// Packed butterfly on bit KK applied to BOTH pipelines (4 rows) with ONE
// sincos evaluation (column-determined, row-independent). 8 independent
// pk-FMA chains per p: high ILP.
template<int KK>
__device__ __forceinline__ void bfly2(float2v (&ra)[8], float2v (&rb)[8],
                                      const float (&th)[4]) {
    #pragma unroll
    for (int p = 0; p < 4; ++p) {
        const int e0 = ((p >> KK) << (KK + 1)) | (p & ((1 << KK) - 1));
        const int e1 = e0 | (1 << KK);
        const float c = __builtin_amdgcn_cosf(th[p]);
        const float s = __builtin_amdgcn_sinf(th[p]);
        const float2v cv = {c, c};
        const float2v sv = {s, s};
        const float2v a0 = ra[e0], a1 = ra[e1];
        ra[e0] = __builtin_elementwise_fma(cv, a0, sv * a1);
        ra[e1] = __builtin_elementwise_fma(cv, a1, -(sv * a0));
        const float2v b0 = rb[e0], b1 = rb[e1];
        rb[e0] = __builtin_elementwise_fma(cv, b0, sv * b1);
        rb[e1] = __builtin_elementwise_fma(cv, b1, -(sv * b0));
    }
}

// 3 butterfly steps; SINGLE theta buffer, distance-1 prefetch pinned after
// each last use. R12 lesson: the 3rd block/CU must come from REMOVING state
// (te/to pair -> te, -4 VGPR), not from allocator pressure. The exposed
// ~200cy L2 latency per step is what the bought occupancy (6 waves/SIMD)
// exists to absorb.
template<int BASE>
__device__ __forceinline__ void group3(float2v (&ra)[8], float2v (&rb)[8],
        float (&te)[4], const float* __restrict__ tb) {
    bfly2<2>(ra, rb, te);
    if constexpr (BASE + 1 < NSTEPS) { ldth4(te, tb + (BASE + 1) * 2048); SB(); }
    bfly2<1>(ra, rb, te);
    if constexpr (BASE + 2 < NSTEPS) { ldth4(te, tb + (BASE + 2) * 2048); SB(); }
    bfly2<0>(ra, rb, te);
    if constexpr (BASE + 3 < NSTEPS) { ldth4(te, tb + (BASE + 3) * 2048); SB(); }
}

// Both pipelines share ONE 32 KiB b64 buffer, transposed back-to-back.
// Hazards: wA->rA cross-thread (sync1); rA->wB cross-thread (sync2);
// wB->rB cross-thread (sync3); rB->next wA same-thread (R9 bijection).
#define TRANS(QS, QDm) do {                                                   \
    _Pragma("unroll")                                                         \
    for (int e = 0; e < 8; ++e)                                               \
        lds[SWZ(QS(e))] = rpA[e];                                             \
    __syncthreads();                                                          \
    _Pragma("unroll")                                                         \
    for (int e = 0; e < 8; ++e)                                               \
        rpA[e] = lds[SWZ(QDm(e))];                                            \
    __syncthreads();                                                          \
    _Pragma("unroll")                                                         \
    for (int e = 0; e < 8; ++e)                                               \
        lds[SWZ(QS(e))] = rpB[e];                                             \
    __syncthreads();                                                         \
    _Pragma("unroll")                                                         \
    for (int e = 0; e < 8; ++e)                                               \
        rpB[e] = lds[SWZ(QDm(e))];                                            \
} while (0)

// (512,2): NO allocator pressure (R12 spilled at (512,6)). Target: natural
// VGPR <= 42 via real state removal -> floor(256/V) = 6 waves/SIMD ->
// 3 blocks/CU (tier model validated R10-R12).
__global__ __launch_bounds__(512, 2)
void bfly_kernel(const float* __restrict__ X,
                 const float* __restrict__ tab,
                 float* __restrict__ Y) {
    __shared__ float2v lds[4096];      // 32 KiB, shared by both pipelines
    const int t = threadIdx.x;
    const size_t row0 = (size_t)blockIdx.x * 4;

    const float* tb = tab + t * 4;
    float te[4];
    ldth4(te, tb + 0 * 2048);
    SB();

    float2v rpA[8], rpB[8];            // A: rows 0,1  B: rows 2,3
    {
        const float* x0 = X + row0 * 4096;
        const float* x1 = x0 + 4096;
        const float* x2 = x0 + 8192;
        const float* x3 = x0 + 12288;
        #pragma unroll
        for (int e = 0; e < 8; ++e) {
            const int a = QA(e);   // consecutive lanes, consecutive addresses
            rpA[e].x = x0[a];
            rpA[e].y = x1[a];
            rpB[e].x = x2[a];
            rpB[e].y = x3[a];
        }
    }

    group3<0 >(rpA, rpB, te, tb);   TRANS(QA, QB);   // steps 0..2   bits 11..9
    group3<3 >(rpA, rpB, te, tb);   TRANS(QB, QC);   // steps 3..5   bits 8..6
    group3<6 >(rpA, rpB, te, tb);   TRANS(QC, QD);   // steps 6..8   bits 5..3
    group3<9 >(rpA, rpB, te, tb);   TRANS(QD, QA);   // steps 9..11  bits 2..0
    group3<12>(rpA, rpB, te, tb);   TRANS(QA, QB);   // steps 12..14 bits 11..9
    group3<15>(rpA, rpB, te, tb);   TRANS(QB, QC);   // steps 15..17 bits 8..6
    group3<18>(rpA, rpB, te, tb);   TRANS(QC, QD);   // steps 18..20 bits 5..3
    group3<21>(rpA, rpB, te, tb);                    // steps 21..23 bits 2..0

    // QD layout: thread t holds 8 consecutive columns at t*8, 4 rows.
    {
        float* y0 = Y + row0 * 4096 + (t << 3);
        float* y1 = y0 + 4096;
        float* y2 = y0 + 8192;
        float* y3 = y0 + 12288;
        float4 v;
        v.x = rpA[0].x; v.y = rpA[1].x; v.z = rpA[2].x; v.w = rpA[3].x;
        *(float4*)&y0[0] = v;
        v.x = rpA[4].x; v.y = rpA[5].x; v.z = rpA[6].x; v.w = rpA[7].x;
        *(float4*)&y0[4] = v;
        v.x = rpA[0].y; v.y = rpA[1].y; v.z = rpA[2].y; v.w = rpA[3].y;
        *(float4*)&y1[0] = v;
        v.x = rpA[4].y; v.y = rpA[5].y; v.z = rpA[6].y; v.w = rpA[7].y;
        *(float4*)&y1[4] = v;
        v.x = rpB[0].x; v.y = rpB[1].x; v.z = rpB[2].x; v.w = rpB[3].x;
        *(float4*)&y2[0] = v;
        v.x = rpB[4].x; v.y = rpB[5].x; v.z = rpB[6].x; v.w = rpB[7].x;
        *(float4*)&y2[4] = v;
        v.x = rpB[0].y; v.y = rpB[1].y; v.z = rpB[2].y; v.w = rpB[3].y;
        *(float4*)&y3[0] = v;
        v.x = rpB[4].y; v.y = rpB[5].y; v.z = rpB[6].y; v.w = rpB[7].y;
        *(float4*)&y3[4] = v;
    }
}

extern "C" void kernel_launch(void* const* d_in, const int* in_sizes, int n_in,
                              void* d_out, int out_size, void* d_ws, size_t ws_size,
                              hipStream_t stream) {
    const float* X      = (const float*)d_in[0];
    const float* params = (const float*)d_in[1];
    float* out = (float*)d_out;
    float* tab = (float*)d_ws;   // 24*2048*4 = 196,608 bytes (theta only)

    hipLaunchKernelGGL(build_tab_kernel,
                       dim3((NSTEPS * HALFW + 255) / 256), dim3(256), 0, stream,
                       params, tab);
    hipLaunchKernelGGL(bfly_kernel,
                       dim3(8192 / 4), dim3(512), 0, stream,
                       X, tab, out);
}

// Round 14
// 81.788 us; speedup vs baseline: 1.1901x; 1.1225x over previous
//
#include <hip/hip_runtime.h>

#define NSTEPS 24
#define HALFW  2048
#define INV2PI 0.15915494309189535f

typedef float float2v __attribute__((ext_vector_type(2)));

// R10 swizzle (bijective triangular XOR) — verified per-16-lane-injective
// for all four maps; measured 2.1M conflict-cycles (~3.4us/CU, acceptable).
#define SWZ(q) ((q) ^ (((q) >> 4) & 31) ^ (((q) >> 3) & 8))

// Phase maps for 512 threads x 8 elems (R10-verified): lane bits stay in
// q[3:0] at load (QA) and store (QD) phases => dense coalescing.
#define QA(e) (((e) << 9) | t)                                  // e in 11..9
#define QB(e) ((((t) >> 6) << 9) | ((e) << 6) | ((t) & 63))     // e in 8..6
#define QC(e) ((((t) >> 3) << 6) | ((e) << 3) | ((t) & 7))      // e in 5..3
#define QD(e) (((t) << 3) | (e))                                // e in 2..0

#define SB() __builtin_amdgcn_sched_barrier(0)

// tab[d*2048 + t*4 + p] = theta/(2*pi). R10/R11-verified derivation.
__global__ void build_tab_kernel(const float* __restrict__ params,
                                 float* __restrict__ tab) {
    int idx = blockIdx.x * 256 + threadIdx.x;
    if (idx >= NSTEPS * HALFW) return;
    int d  = idx >> 11;
    int j  = idx & (HALFW - 1);
    int t  = j >> 2;              // 0..511
    int p  = j & 3;               // pair index (2 bits)
    int ph = d / 3;               // phase 0..7, map = ph & 3
    int k  = 2 - (d % 3);         // butterfly bit within the 3-bit group
    int e0 = ((p >> k) << (k + 1)) | (p & ((1 << k) - 1)); // insert 0 at bit k
    int q0;
    switch (ph & 3) {
        case 0:  q0 = (e0 << 9) | t; break;
        case 1:  q0 = ((t >> 6) << 9) | (e0 << 6) | (t & 63); break;
        case 2:  q0 = ((t >> 3) << 6) | (e0 << 3) | (t & 7); break;
        default: q0 = (t << 3) | e0; break;
    }
    int dd = d % 12;
    int l = ((q0 << dd) | (q0 >> (12 - dd))) & 0xFFF;       // rotl12(q0, dd)
    l &= 0x7FF;
    float theta = params[l * NSTEPS + d];   // params (2048, 24) row-major
    tab[idx] = theta * INV2PI;
}

// 4-float theta load (one dwordx4, SROA-safe scalar unpack).
__device__ __forceinline__ void ldth4(float (&dst)[4], const float* __restrict__ p) {
    float4 q = *(const float4*)p;
    dst[0] = q.x; dst[1] = q.y; dst[2] = q.z; dst[3] = q.w;
}

// Packed butterfly on bit KK applied to BOTH pipelines (4 rows) with ONE
// sincos evaluation (column-determined, row-independent). 8 independent
// pk-FMA chains per p: high ILP.
template<int KK>
__device__ __forceinline__ void bfly2(float2v (&ra)[8], float2v (&rb)[8],
                                      const float (&th)[4]) {
    #pragma unroll
    for (int p = 0; p < 4; ++p) {
        const int e0 = ((p >> KK) << (KK + 1)) | (p & ((1 << KK) - 1));
        const int e1 = e0 | (1 << KK);
        const float c = __builtin_amdgcn_cosf(th[p]);
        const float s = __builtin_amdgcn_sinf(th[p]);
        const float2v cv = {c, c};
        const float2v sv = {s, s};
        const float2v a0 = ra[e0], a1 = ra[e1];
        ra[e0] = __builtin_elementwise_fma(cv, a0, sv * a1);
        ra[e1] = __builtin_elementwise_fma(cv, a1, -(sv * a0));
        const float2v b0 = rb[e0], b1 = rb[e1];
        rb[e0] = __builtin_elementwise_fma(cv, b0, sv * b1);
        rb[e1] = __builtin_elementwise_fma(cv, b1, -(sv * b0));
    }
}

// 3 butterfly steps (one phase) on both pipelines; theta dbuf te/to,
// distance-2 prefetch pinned after each last use (R11 record-holder
// pattern; R13 proved distance-1 regresses).
template<int BASE>
__device__ __forceinline__ void group3(float2v (&ra)[8], float2v (&rb)[8],
        float (&te)[4], float (&to)[4], const float* __restrict__ tb) {
    if constexpr ((BASE & 1) == 0) {
        bfly2<2>(ra, rb, te);
        if constexpr (BASE + 2 < NSTEPS) { ldth4(te, tb + (BASE + 2) * 2048); SB(); }
        bfly2<1>(ra, rb, to);
        if constexpr (BASE + 3 < NSTEPS) { ldth4(to, tb + (BASE + 3) * 2048); SB(); }
        bfly2<0>(ra, rb, te);
        if constexpr (BASE + 4 < NSTEPS) { ldth4(te, tb + (BASE + 4) * 2048); SB(); }
    } else {
        bfly2<2>(ra, rb, to);
        if constexpr (BASE + 2 < NSTEPS) { ldth4(to, tb + (BASE + 2) * 2048); SB(); }
        bfly2<1>(ra, rb, te);
        if constexpr (BASE + 3 < NSTEPS) { ldth4(te, tb + (BASE + 3) * 2048); SB(); }
        bfly2<0>(ra, rb, to);
        if constexpr (BASE + 4 < NSTEPS) { ldth4(to, tb + (BASE + 4) * 2048); SB(); }
    }
}

// Double-buffered transpose: pipeline A in ldsA, pipeline B in ldsB —
// removes the 3-sync serialization of the shared buffer: ONE barrier per
// transition (21 -> 7 total). Sync elision between this TRANS's read and
// the next TRANS's write is the R9-proven same-thread bijection (read slot
// SWZ(QDm_k(e)) == next write slot SWZ(QS_{k+1}(e)) since QS_{k+1}=QDm_k;
// data dependence orders them in-thread). Write/read addresses computed
// once, shared by both buffers.
#define TRANS(QS, QDm) do {                                                   \
    _Pragma("unroll")                                                         \
    for (int e = 0; e < 8; ++e) {                                             \
        const int a = SWZ(QS(e));                                             \
        ldsA[a] = rpA[e];                                                     \
        ldsB[a] = rpB[e];                                                     \
    }                                                                         \
    __syncthreads();                                                          \
    _Pragma("unroll")                                                         \
    for (int e = 0; e < 8; ++e) {                                             \
        const int a = SWZ(QDm(e));                                            \
        rpA[e] = ldsA[a];                                                     \
        rpB[e] = ldsB[a];                                                     \
    }                                                                         \
} while (0)

// (512,2): no allocator pressure (R12 spill lesson). VGPR ~44 -> 2 blocks/CU
// (tier model, validated R10-R13); 64 KiB LDS/block -> 128 KiB/CU <= 160 OK,
// LDS cap = 2 blocks/CU = same as VGPR cap: no occupancy loss.
__global__ __launch_bounds__(512, 2)
void bfly_kernel(const float* __restrict__ X,
                 const float* __restrict__ tab,
                 float* __restrict__ Y) {
    __shared__ float2v ldsA[4096];     // 32 KiB, pipeline A (rows 0,1)
    __shared__ float2v ldsB[4096];     // 32 KiB, pipeline B (rows 2,3)
    const int t = threadIdx.x;
    const size_t row0 = (size_t)blockIdx.x * 4;

    const float* tb = tab + t * 4;
    float te[4], to[4];
    ldth4(te, tb + 0 * 2048);
    ldth4(to, tb + 1 * 2048);
    SB();

    float2v rpA[8], rpB[8];            // A: rows 0,1  B: rows 2,3
    {
        const float* x0 = X + row0 * 4096;
        const float* x1 = x0 + 4096;
        const float* x2 = x0 + 8192;
        const float* x3 = x0 + 12288;
        #pragma unroll
        for (int e = 0; e < 8; ++e) {
            const int a = QA(e);   // consecutive lanes, consecutive addresses
            rpA[e].x = x0[a];
            rpA[e].y = x1[a];
            rpB[e].x = x2[a];
            rpB[e].y = x3[a];
        }
    }

    group3<0 >(rpA, rpB, te, to, tb);   TRANS(QA, QB);   // steps 0..2   bits 11..9
    group3<3 >(rpA, rpB, te, to, tb);   TRANS(QB, QC);   // steps 3..5   bits 8..6
    group3<6 >(rpA, rpB, te, to, tb);   TRANS(QC, QD);   // steps 6..8   bits 5..3
    group3<9 >(rpA, rpB, te, to, tb);   TRANS(QD, QA);   // steps 9..11  bits 2..0
    group3<12>(rpA, rpB, te, to, tb);   TRANS(QA, QB);   // steps 12..14 bits 11..9
    group3<15>(rpA, rpB, te, to, tb);   TRANS(QB, QC);   // steps 15..17 bits 8..6
    group3<18>(rpA, rpB, te, to, tb);   TRANS(QC, QD);   // steps 18..20 bits 5..3
    group3<21>(rpA, rpB, te, to, tb);                    // steps 21..23 bits 2..0

    // QD layout: thread t holds 8 consecutive columns at t*8, 4 rows.
    {
        float* y0 = Y + row0 * 4096 + (t << 3);
        float* y1 = y0 + 4096;
        float* y2 = y0 + 8192;
        float* y3 = y0 + 12288;
        float4 v;
        v.x = rpA[0].x; v.y = rpA[1].x; v.z = rpA[2].x; v.w = rpA[3].x;
        *(float4*)&y0[0] = v;
        v.x = rpA[4].x; v.y = rpA[5].x; v.z = rpA[6].x; v.w = rpA[7].x;
        *(float4*)&y0[4] = v;
        v.x = rpA[0].y; v.y = rpA[1].y; v.z = rpA[2].y; v.w = rpA[3].y;
        *(float4*)&y1[0] = v;
        v.x = rpA[4].y; v.y = rpA[5].y; v.z = rpA[6].y; v.w = rpA[7].y;
        *(float4*)&y1[4] = v;
        v.x = rpB[0].x; v.y = rpB[1].x; v.z = rpB[2].x; v.w = rpB[3].x;
        *(float4*)&y2[0] = v;
        v.x = rpB[4].x; v.y = rpB[5].x; v.z = rpB[6].x; v.w = rpB[7].x;
        *(float4*)&y2[4] = v;
        v.x = rpB[0].y; v.y = rpB[1].y; v.z = rpB[2].y; v.w = rpB[3].y;
        *(float4*)&y3[0] = v;
        v.x = rpB[4].y; v.y = rpB[5].y; v.z = rpB[6].y; v.w = rpB[7].y;
        *(float4*)&y3[4] = v;
    }
}

extern "C" void kernel_launch(void* const* d_in, const int* in_sizes, int n_in,
                              void* d_out, int out_size, void* d_ws, size_t ws_size,
                              hipStream_t stream) {
    const float* X      = (const float*)d_in[0];
    const float* params = (const float*)d_in[1];
    float* out = (float*)d_out;
    float* tab = (float*)d_ws;   // 24*2048*4 = 196,608 bytes (theta only)

    hipLaunchKernelGGL(build_tab_kernel,
                       dim3((NSTEPS * HALFW + 255) / 256), dim3(256), 0, stream,
                       params, tab);
    hipLaunchKernelGGL(bfly_kernel,
                       dim3(8192 / 4), dim3(512), 0, stream,
                       X, tab, out);
}